// Round 7
// baseline (215.138 us; speedup 1.0000x reference)
//
#include <hip/hip_runtime.h>
#include <math.h>

#define NB 64
#define NA 5
#define NC 80
#define NH 38
#define NW 38
#define MAXB 50
#define PLANE (NH*NW)          // 1444
#define PER_B (NA*PLANE)       // 7220
#define NCH (5+NC)             // 85
#define CPB 482                // cells per block (2 per thread)
#define MAIN_BX 15             // ceil(7220/482)
#define NPART (MAIN_BX * NB)   // 960

__constant__ float c_aw[5] = {1.3221f, 3.19275f, 5.05587f, 9.47112f, 11.2364f};
__constant__ float c_ah[5] = {1.73145f, 4.00944f, 8.09892f, 4.84053f, 10.0071f};

struct Entry {
    int   fidx;    // global flat index into N, or -1 if not a winner
    int   tcls;
    float cm, tc0, tc1, tc2, tc3, tconf;
};

__device__ inline float fexp(float x)     { return __expf(x); }
__device__ inline float flog(float x)     { return __logf(x); }
__device__ inline float fsigmoid(float x) { return __builtin_amdgcn_rcpf(1.f + __expf(-x)); }

// ---- Fused kernel: wave-0 GT prep (LDS) + 2-cell coord/conf + wave-CE ------
__global__ __launch_bounds__(256)
void main_kernel(const float* __restrict__ out, const float* __restrict__ target,
                 float* __restrict__ partial) {
    const int b   = blockIdx.y;
    const int bx  = blockIdx.x;
    const int tid = threadIdx.x;

    __shared__ float4 sbox[MAXB];   // gt corners: x1,y1,x2,y2
    __shared__ float  sarea[MAXB];  // 0.6 * gt area (pre-scaled for the compare)
    __shared__ Entry  sent[MAXB];
    __shared__ int    sfx[64];
    __shared__ int    snv;
    __shared__ int    sobj_cnt;
    __shared__ int    sobj_idx[MAXB];
    __shared__ short  smap[CPB];    // local cell -> winner entry

    if (tid == 0) sobj_cnt = 0;
    smap[tid] = -1;
    if (tid < CPB - 256) smap[256 + tid] = -1;

    // ---------------- wave-0 prep (redundant per block, all in LDS) --------
    if (tid < 64) {
        const float* tb = target + b * MAXB * 5;
        int t = tid;
        bool has = (t < MAXB);
        float cls = 0.f, x = 0.f, y = 0.f, w = 0.f, h = 0.f;
        if (has) {
            cls = tb[t * 5 + 0];
            x   = tb[t * 5 + 1];
            y   = tb[t * 5 + 2];
            w   = tb[t * 5 + 3];
            h   = tb[t * 5 + 4];
        }
        unsigned long long mask = __ballot(has && (x > 0.f));
        bool valid = has && (((~mask) & ((1ull << (t + 1)) - 1ull)) == 0ull);

        float gx = x * NW, gy = y * NH, gw = w * NW, gh = h * NH;

        int best = 0; float bestr = -1.f;
        #pragma unroll
        for (int a = 0; a < NA; a++) {
            float inter = fminf(c_aw[a], gw) * fminf(c_ah[a], gh);
            float uni   = c_aw[a] * c_ah[a] + gw * gh - inter;
            float r = inter / fmaxf(uni, 1e-10f);
            if (r > bestr) { bestr = r; best = a; }
        }
        int gi = min(max((int)gx, 0), NW - 1);
        int gj = min(max((int)gy, 0), NH - 1);
        int fidx = b * PER_B + best * PLANE + gj * NW + gi;

        float iou_sel = 0.f;
        if (valid) {
            int base = ((b * NA + best) * NCH) * PLANE + gj * NW + gi;
            float o0 = out[base];
            float o1 = out[base + PLANE];
            float o2 = out[base + 2 * PLANE];
            float o3 = out[base + 3 * PLANE];
            float px = fsigmoid(o0) + (float)gi;
            float py = fsigmoid(o1) + (float)gj;
            float pw = fexp(o2) * c_aw[best];
            float ph = fexp(o3) * c_ah[best];
            float iw = fmaxf(fminf(gx + gw*0.5f, px + pw*0.5f) - fmaxf(gx - gw*0.5f, px - pw*0.5f), 0.f);
            float ih = fmaxf(fminf(gy + gh*0.5f, py + ph*0.5f) - fmaxf(gy - gh*0.5f, py - ph*0.5f), 0.f);
            float inter = iw * ih;
            float uni = gw * gh + pw * ph - inter;
            iou_sel = inter / fmaxf(uni, 1e-10f);
        }

        // winner = last valid box with this fidx (wave-lockstep LDS)
        sfx[t] = valid ? fidx : -1;
        bool winner = valid;
        if (valid) {
            for (int s = t + 1; s < MAXB; s++)
                if (sfx[s] == fidx) { winner = false; break; }
        }

        if (has) {
            sbox[t]  = make_float4(gx - gw*0.5f, gy - gh*0.5f, gx + gw*0.5f, gy + gh*0.5f);
            sarea[t] = 0.6f * gw * gh;
            Entry e;
            e.fidx  = winner ? fidx : -1;
            e.tcls  = (int)cls;
            e.cm    = 2.f - w * h;
            e.tc0   = gx - (float)gi;
            e.tc1   = gy - (float)gj;
            e.tc2   = flog(gw / c_aw[best]);
            e.tc3   = flog(gh / c_ah[best]);
            e.tconf = iou_sel;
            sent[t] = e;
        }
        if (t == 0) {
            unsigned long long nm = ~mask;
            snv = min(__ffsll((unsigned long long)nm) - 1, MAXB);
        }
    }
    __syncthreads();

    // ------- block-local obj list + O(1) cell->entry map --------------------
    const int cbase = bx * CPB;               // local cell range [cbase, cbase+CPB)
    const int nlo   = b * PER_B + cbase;
    if (tid < MAXB) {
        int f = sent[tid].fidx;
        if (f >= nlo && f < nlo + CPB) {
            int slot = atomicAdd(&sobj_cnt, 1);
            sobj_idx[slot] = tid;
            smap[f - nlo] = (short)tid;       // unique per cell (deduped winners)
        }
    }
    __syncthreads();

    const int wid = tid >> 6, lane = tid & 63;
    const int oc = sobj_cnt;

    // ------- CE gather: 2 entries/wave, loads issued BEFORE the cell pass ---
    int   eA = (wid < oc) ? sobj_idx[wid] : -1;
    int   eB = (wid + 4 < oc) ? sobj_idx[wid + 4] : -1;
    float vA1 = 0.f, vA2 = -INFINITY, vB1 = 0.f, vB2 = -INFINITY;
    if (eA >= 0) {
        int rel = sent[eA].fidx - b * PER_B;
        int a = rel / PLANE, pos = rel - a * PLANE;
        const float* cp = out + ((b * NA + a) * NCH + 5) * PLANE + pos;
        vA1 = cp[lane * PLANE];
        if (lane < NC - 64) vA2 = cp[(64 + lane) * PLANE];
    }
    if (eB >= 0) {
        int rel = sent[eB].fidx - b * PER_B;
        int a = rel / PLANE, pos = rel - a * PLANE;
        const float* cp = out + ((b * NA + a) * NCH + 5) * PLANE + pos;
        vB1 = cp[lane * PLANE];
        if (lane < NC - 64) vB2 = cp[(64 + lane) * PLANE];
    }

    // ---------------- two cells per thread: issue all 10 loads first --------
    int  c0 = cbase + tid;                    // local cell in [0, PER_B)
    int  c1 = cbase + 256 + tid;
    bool act0 = (c0 < PER_B);
    bool act1 = (tid < CPB - 256) && (c1 < PER_B);

    int a0 = 0, i0 = 0, j0 = 0, a1 = 0, i1 = 0, j1 = 0;
    float o0_0=0.f,o1_0=0.f,o2_0=0.f,o3_0=0.f,o4_0=0.f;
    float o0_1=0.f,o1_1=0.f,o2_1=0.f,o3_1=0.f,o4_1=0.f;
    if (act0) {
        a0 = c0 / PLANE; int pos = c0 - a0 * PLANE;
        j0 = pos / NW;   i0 = pos - j0 * NW;
        const float* p = out + ((b * NA + a0) * NCH) * PLANE + pos;
        o0_0 = p[0]; o1_0 = p[PLANE]; o2_0 = p[2*PLANE]; o3_0 = p[3*PLANE]; o4_0 = p[4*PLANE];
    }
    if (act1) {
        a1 = c1 / PLANE; int pos = c1 - a1 * PLANE;
        j1 = pos / NW;   i1 = pos - j1 * NW;
        const float* p = out + ((b * NA + a1) * NCH) * PLANE + pos;
        o0_1 = p[0]; o1_1 = p[PLANE]; o2_1 = p[2*PLANE]; o3_1 = p[3*PLANE]; o4_1 = p[4*PLANE];
    }

    // decoded predictions (inactive lanes compute garbage-free defaults)
    float s0_0 = fsigmoid(o0_0), s1_0 = fsigmoid(o1_0), cf_0 = fsigmoid(o4_0);
    float pw0 = fexp(o2_0) * c_aw[a0], ph0 = fexp(o3_0) * c_ah[a0];
    float px1_0 = s0_0 + (float)i0 - pw0 * 0.5f, px2_0 = px1_0 + pw0;
    float py1_0 = s1_0 + (float)j0 - ph0 * 0.5f, py2_0 = py1_0 + ph0;
    float ap0 = 0.6f * pw0 * ph0;

    float s0_1 = fsigmoid(o0_1), s1_1 = fsigmoid(o1_1), cf_1 = fsigmoid(o4_1);
    float pw1 = fexp(o2_1) * c_aw[a1], ph1 = fexp(o3_1) * c_ah[a1];
    float px1_1 = s0_1 + (float)i1 - pw1 * 0.5f, px2_1 = px1_1 + pw1;
    float py1_1 = s1_1 + (float)j1 - ph1 * 0.5f, py2_1 = py1_1 + ph1;
    float ap1 = 0.6f * pw1 * ph1;

    // shared pass over GT boxes: iou > 0.6  <=>  1.6*inter > 0.6*(ap+area)
    bool g06_0 = false, g06_1 = false;
    int nv = snv;
    for (int s = 0; s < nv; s++) {
        float4 g = sbox[s];
        float sa = sarea[s];
        float iw0 = fmaxf(fminf(px2_0, g.z) - fmaxf(px1_0, g.x), 0.f);
        float ih0 = fmaxf(fminf(py2_0, g.w) - fmaxf(py1_0, g.y), 0.f);
        g06_0 = g06_0 || (1.6f * iw0 * ih0 > ap0 + sa);
        float iw1 = fmaxf(fminf(px2_1, g.z) - fmaxf(px1_1, g.x), 0.f);
        float ih1 = fmaxf(fminf(py2_1, g.w) - fmaxf(py1_1, g.y), 0.f);
        g06_1 = g06_1 || (1.6f * iw1 * ih1 > ap1 + sa);
    }

    float part = 0.f;
    if (act0) {
        float cm = 0.01f, tc0 = 0.5f, tc1 = 0.5f, tc2 = 0.f, tc3 = 0.f, tcf = 0.f;
        bool is_obj = false;
        int e = smap[tid];
        if (e >= 0) {
            is_obj = true;
            cm  = sent[e].cm;
            tc0 = sent[e].tc0; tc1 = sent[e].tc1;
            tc2 = sent[e].tc2; tc3 = sent[e].tc3;
            tcf = sent[e].tconf;
        }
        float cmask = is_obj ? 5.f : (g06_0 ? 0.f : 1.f);
        float d;
        d = (s0_0 - tc0) * cm;    part += d * d;
        d = (s1_0 - tc1) * cm;    part += d * d;
        d = (o2_0 - tc2) * cm;    part += d * d;
        d = (o3_0 - tc3) * cm;    part += d * d;
        d = (cf_0 - tcf) * cmask; part += d * d;
    }
    if (act1) {
        float cm = 0.01f, tc0 = 0.5f, tc1 = 0.5f, tc2 = 0.f, tc3 = 0.f, tcf = 0.f;
        bool is_obj = false;
        int e = smap[256 + tid];
        if (e >= 0) {
            is_obj = true;
            cm  = sent[e].cm;
            tc0 = sent[e].tc0; tc1 = sent[e].tc1;
            tc2 = sent[e].tc2; tc3 = sent[e].tc3;
            tcf = sent[e].tconf;
        }
        float cmask = is_obj ? 5.f : (g06_1 ? 0.f : 1.f);
        float d;
        d = (s0_1 - tc0) * cm;    part += d * d;
        d = (s1_1 - tc1) * cm;    part += d * d;
        d = (o2_1 - tc2) * cm;    part += d * d;
        d = (o3_1 - tc3) * cm;    part += d * d;
        d = (cf_1 - tcf) * cmask; part += d * d;
    }

    // ---------------- finish CE with the in-flight gathers ------------------
    if (eA >= 0) {
        float mx = fmaxf(vA1, vA2);
        for (int off = 32; off > 0; off >>= 1) mx = fmaxf(mx, __shfl_xor(mx, off));
        float s = fexp(vA1 - mx) + ((lane < NC - 64) ? fexp(vA2 - mx) : 0.f);
        for (int off = 32; off > 0; off >>= 1) s += __shfl_xor(s, off);
        int tc = sent[eA].tcls;
        float tv = (tc < 64) ? __shfl(vA1, tc) : __shfl(vA2, tc - 64);
        if (lane == 0) part += mx + flog(s) - tv;
    }
    if (eB >= 0) {
        float mx = fmaxf(vB1, vB2);
        for (int off = 32; off > 0; off >>= 1) mx = fmaxf(mx, __shfl_xor(mx, off));
        float s = fexp(vB1 - mx) + ((lane < NC - 64) ? fexp(vB2 - mx) : 0.f);
        for (int off = 32; off > 0; off >>= 1) s += __shfl_xor(s, off);
        int tc = sent[eB].tcls;
        float tv = (tc < 64) ? __shfl(vB1, tc) : __shfl(vB2, tc - 64);
        if (lane == 0) part += mx + flog(s) - tv;
    }
    // rare leftovers (more than 8 winners in one block)
    for (int e = 8 + wid; e < oc; e += 4) {
        Entry ent = sent[sobj_idx[e]];
        int rel = ent.fidx - b * PER_B;
        int a = rel / PLANE, pos = rel - a * PLANE;
        const float* cp = out + ((b * NA + a) * NCH + 5) * PLANE + pos;
        float w1 = cp[lane * PLANE];
        float w2 = (lane < NC - 64) ? cp[(64 + lane) * PLANE] : -INFINITY;
        float mx = fmaxf(w1, w2);
        for (int off = 32; off > 0; off >>= 1) mx = fmaxf(mx, __shfl_xor(mx, off));
        float s = fexp(w1 - mx) + ((lane < NC - 64) ? fexp(w2 - mx) : 0.f);
        for (int off = 32; off > 0; off >>= 1) s += __shfl_xor(s, off);
        float tv = (ent.tcls < 64) ? __shfl(w1, ent.tcls) : __shfl(w2, ent.tcls - 64);
        if (lane == 0) part += mx + flog(s) - tv;
    }

    // ---------------- block reduction (4 waves of 64) -----------------------
    for (int off = 32; off > 0; off >>= 1) part += __shfl_down(part, off);
    __shared__ float wsum[4];
    if (lane == 0) wsum[wid] = part;
    __syncthreads();
    if (tid == 0)
        partial[b * MAIN_BX + bx] = wsum[0] + wsum[1] + wsum[2] + wsum[3];
}

// ---------------- final reduction (1 block), writes d_out -------------------
__global__ __launch_bounds__(256)
void final_kernel(const float* __restrict__ partial, float* __restrict__ loss) {
    int tid = threadIdx.x;
    float s = 0.f;
    for (int i = tid; i < NPART; i += 256) s += partial[i];
    for (int off = 32; off > 0; off >>= 1) s += __shfl_down(s, off);
    __shared__ float wsum[4];
    int wid = tid >> 6, lane = tid & 63;
    if (lane == 0) wsum[wid] = s;
    __syncthreads();
    if (tid == 0)
        loss[0] = (wsum[0] + wsum[1] + wsum[2] + wsum[3]) * (1.0f / NB);
}

extern "C" void kernel_launch(void* const* d_in, const int* in_sizes, int n_in,
                              void* d_out, int out_size, void* d_ws, size_t ws_size,
                              hipStream_t stream) {
    const float* out    = (const float*)d_in[0];
    const float* target = (const float*)d_in[1];
    float* loss    = (float*)d_out;
    float* partial = (float*)d_ws;     // NPART floats

    dim3 grid(MAIN_BX, NB);
    main_kernel<<<grid, 256, 0, stream>>>(out, target, partial);
    final_kernel<<<1, 256, 0, stream>>>(partial, loss);
}